// Round 1
// baseline (4579.438 us; speedup 1.0000x reference)
//
#include <hip/hip_runtime.h>
#include <cstddef>

constexpr int IMG = 256;
constexpr int NPIX = 65536;

// ---------------------------------------------------------------------------
// Direct 3x3 conv, padding 1, NCHW. One block = 16x16 pixel tile x 16 couts.
// Weights read with block-uniform indices -> scalar loads (s_load), input
// patch staged in LDS. wrow = elements per cout row of the weight tensor
// (= total_cin*9; lets us run a cin-slice of a bigger conv for fused concat).
// ---------------------------------------------------------------------------
template<int CIN, bool LRELU, bool ACCUM>
__global__ __launch_bounds__(256) void conv3x3_k(
    const float* __restrict__ in, const float* __restrict__ w, int wrow,
    const float* __restrict__ bias, float* __restrict__ out, int cout)
{
  __shared__ float sIn[4][18 * 18];
  const int tid = threadIdx.x;
  const int tile = blockIdx.x;
  const int ty0 = (tile >> 4) << 4;
  const int tx0 = (tile & 15) << 4;
  int co0 = blockIdx.y * 16;
  if (co0 + 16 > cout) co0 = cout - 16;   // tail: overlap-recompute, same values
  const int py = tid >> 4, px = tid & 15;
  const int oy = ty0 + py, ox = tx0 + px;

  float acc[16];
#pragma unroll
  for (int i = 0; i < 16; ++i) acc[i] = 0.f;

  for (int c0 = 0; c0 < CIN; c0 += 4) {
    __syncthreads();
    for (int i = tid; i < 4 * 324; i += 256) {
      int cs = i / 324, r = i - cs * 324;
      int ry = r / 18, rx = r - ry * 18;
      int gy = ty0 - 1 + ry, gx = tx0 - 1 + rx;
      float v = 0.f;
      if ((unsigned)gy < (unsigned)IMG && (unsigned)gx < (unsigned)IMG)
        v = in[(size_t)(c0 + cs) * NPIX + gy * IMG + gx];
      sIn[cs][r] = v;
    }
    __syncthreads();
    const float* wp = w + (size_t)co0 * wrow + (size_t)c0 * 9;
#pragma unroll
    for (int cs = 0; cs < 4; ++cs) {
      float v[9];
#pragma unroll
      for (int dy = 0; dy < 3; ++dy)
#pragma unroll
        for (int dx = 0; dx < 3; ++dx)
          v[dy * 3 + dx] = sIn[cs][(py + dy) * 18 + (px + dx)];
#pragma unroll
      for (int co = 0; co < 16; ++co) {
        float a = acc[co];
#pragma unroll
        for (int k = 0; k < 9; ++k)
          a = fmaf(wp[(size_t)co * wrow + cs * 9 + k], v[k], a);
        acc[co] = a;
      }
    }
  }
#pragma unroll
  for (int co = 0; co < 16; ++co) {
    size_t oidx = (size_t)(co0 + co) * NPIX + (size_t)oy * IMG + ox;
    if (ACCUM) {
      out[oidx] += acc[co];
    } else {
      float r = acc[co] + bias[co0 + co];
      if (LRELU) r = (r >= 0.f) ? r : 0.1f * r;
      out[oidx] = r;
    }
  }
}

// ---------------------------------------------------------------------------
// CHW -> HWC transpose of the 64-channel feature map (for vectorized gathers).
// ---------------------------------------------------------------------------
__global__ __launch_bounds__(256) void transpose_k(
    const float* __restrict__ in, float* __restrict__ out)
{
  int pix = blockIdx.x * 256 + threadIdx.x;
#pragma unroll
  for (int c = 0; c < 64; c += 4) {
    float4 v;
    v.x = in[(size_t)(c + 0) * NPIX + pix];
    v.y = in[(size_t)(c + 1) * NPIX + pix];
    v.z = in[(size_t)(c + 2) * NPIX + pix];
    v.w = in[(size_t)(c + 3) * NPIX + pix];
    *reinterpret_cast<float4*>(&out[(size_t)pix * 64 + c]) = v;
  }
}

// ---------------------------------------------------------------------------
// Modulated deformable conv. One thread = one pixel, 64 accumulators.
// offset/mask post-processing (tanh/sigmoid/flow add) fused in.
// featT is HWC. o216 = raw last-conv output (216 ch, CHW).
// Channel map: off_y(g,k)=10*tanh(o216[g*18+2k])+flow[1],
//              off_x(g,k)=10*tanh(o216[g*18+2k+1])+flow[0],
//              mask(g,k)=sigmoid(o216[144+g*9+k]).
// ---------------------------------------------------------------------------
__global__ __launch_bounds__(256, 1) void mdcn_k(
    const float* __restrict__ featT, const float* __restrict__ o216,
    const float* __restrict__ flow, const float* __restrict__ w,
    const float* __restrict__ bias, float* __restrict__ out)
{
  const int pix = blockIdx.x * 256 + threadIdx.x;
  const int h = pix >> 8, x = pix & 255;
  const float fy = flow[NPIX + pix];   // flow[:, ::-1] -> ch0 of off pair += flow[1]
  const float fx = flow[pix];

  float acc[64];
#pragma unroll
  for (int o = 0; o < 64; ++o) acc[o] = 0.f;

  for (int g = 0; g < 8; ++g) {
    float s[72];  // s[k*8 + c']
#pragma unroll
    for (int k = 0; k < 9; ++k) {
      float oyr = o216[(size_t)(g * 18 + 2 * k) * NPIX + pix];
      float oxr = o216[(size_t)(g * 18 + 2 * k + 1) * NPIX + pix];
      float mkr = o216[(size_t)(144 + g * 9 + k) * NPIX + pix];
      float m = 1.f / (1.f + __expf(-mkr));
      float pyf = (float)h + (float)(k / 3 - 1) + 10.f * tanhf(oyr) + fy;
      float pxf = (float)x + (float)(k % 3 - 1) + 10.f * tanhf(oxr) + fx;
      float y0f = floorf(pyf), x0f = floorf(pxf);
      float ly = pyf - y0f, lx = pxf - x0f;
      int y0 = (int)y0f, x0 = (int)x0f;
      int y1 = y0 + 1, x1 = x0 + 1;
      bool vy0 = (unsigned)y0 < (unsigned)IMG, vy1 = (unsigned)y1 < (unsigned)IMG;
      bool vx0 = (unsigned)x0 < (unsigned)IMG, vx1 = (unsigned)x1 < (unsigned)IMG;
      int y0c = min(max(y0, 0), IMG - 1), y1c = min(max(y1, 0), IMG - 1);
      int x0c = min(max(x0, 0), IMG - 1), x1c = min(max(x1, 0), IMG - 1);
      float w00 = (vy0 && vx0) ? (1.f - ly) * (1.f - lx) * m : 0.f;
      float w01 = (vy0 && vx1) ? (1.f - ly) * lx * m : 0.f;
      float w10 = (vy1 && vx0) ? ly * (1.f - lx) * m : 0.f;
      float w11 = (vy1 && vx1) ? ly * lx * m : 0.f;
      const float* p00 = featT + ((size_t)(y0c * IMG + x0c)) * 64 + g * 8;
      const float* p01 = featT + ((size_t)(y0c * IMG + x1c)) * 64 + g * 8;
      const float* p10 = featT + ((size_t)(y1c * IMG + x0c)) * 64 + g * 8;
      const float* p11 = featT + ((size_t)(y1c * IMG + x1c)) * 64 + g * 8;
#pragma unroll
      for (int q = 0; q < 2; ++q) {
        float4 a  = *reinterpret_cast<const float4*>(p00 + 4 * q);
        float4 b4 = *reinterpret_cast<const float4*>(p01 + 4 * q);
        float4 c4 = *reinterpret_cast<const float4*>(p10 + 4 * q);
        float4 d4 = *reinterpret_cast<const float4*>(p11 + 4 * q);
        s[k * 8 + 4 * q + 0] = w00 * a.x + w01 * b4.x + w10 * c4.x + w11 * d4.x;
        s[k * 8 + 4 * q + 1] = w00 * a.y + w01 * b4.y + w10 * c4.y + w11 * d4.y;
        s[k * 8 + 4 * q + 2] = w00 * a.z + w01 * b4.z + w10 * c4.z + w11 * d4.z;
        s[k * 8 + 4 * q + 3] = w00 * a.w + w01 * b4.w + w10 * c4.w + w11 * d4.w;
      }
    }
    // out[o] += sum_{c',k} w[o, g*8+c', k] * s — weights block-uniform -> s_load
    const float* wg = w + g * 72;
#pragma unroll
    for (int o = 0; o < 64; ++o) {
      float a = acc[o];
#pragma unroll
      for (int c = 0; c < 8; ++c)
#pragma unroll
        for (int k = 0; k < 9; ++k)
          a = fmaf(wg[(size_t)o * 576 + c * 9 + k], s[k * 8 + c], a);
      acc[o] = a;
    }
  }
#pragma unroll
  for (int o = 0; o < 64; ++o)
    out[(size_t)o * NPIX + pix] = acc[o] + bias[o];
}

// ---------------------------------------------------------------------------
extern "C" void kernel_launch(void* const* d_in, const int* in_sizes, int n_in,
                              void* d_out, int out_size, void* d_ws, size_t ws_size,
                              hipStream_t stream)
{
  const float* feat[2]  = {(const float*)d_in[0], (const float*)d_in[1]};
  const float* extra[2] = {(const float*)d_in[2], (const float*)d_in[3]};
  const float* flow[2]  = {(const float*)d_in[4], (const float*)d_in[5]};
  const float* ow[2][4];
  const float* ob[2][4];
  for (int br = 0; br < 2; ++br)
    for (int j = 0; j < 4; ++j) {
      ow[br][j] = (const float*)d_in[6 + br * 8 + j * 2];
      ob[br][j] = (const float*)d_in[6 + br * 8 + j * 2 + 1];
    }
  const float* dcnw[2] = {(const float*)d_in[22], (const float*)d_in[24]};
  const float* dcnb[2] = {(const float*)d_in[23], (const float*)d_in[25]};
  const float* fusw = (const float*)d_in[26];
  const float* fusb = (const float*)d_in[27];

  float* ws = (float*)d_ws;
  float* t0 = ws;                       // 64 ch
  float* t1 = ws + (size_t)64 * NPIX;   // 64 ch (conv buffer, then featT)
  float* t2 = ws + (size_t)128 * NPIX;  // 216 ch
  float* outp = (float*)d_out;

  dim3 blk(256);
  for (int br = 0; br < 2; ++br) {
    // offset network
    conv3x3_k<128, true,  false><<<dim3(256, 4),  blk, 0, stream>>>(extra[br], ow[br][0], 128 * 9, ob[br][0], t0, 64);
    conv3x3_k<64,  true,  false><<<dim3(256, 4),  blk, 0, stream>>>(t0, ow[br][1], 64 * 9, ob[br][1], t1, 64);
    conv3x3_k<64,  true,  false><<<dim3(256, 4),  blk, 0, stream>>>(t1, ow[br][2], 64 * 9, ob[br][2], t0, 64);
    conv3x3_k<64,  false, false><<<dim3(256, 14), blk, 0, stream>>>(t0, ow[br][3], 64 * 9, ob[br][3], t2, 216);
    // deformable conv
    transpose_k<<<dim3(256), blk, 0, stream>>>(feat[br], t1);
    mdcn_k<<<dim3(256), blk, 0, stream>>>(t1, t2, flow[br], dcnw[br], dcnb[br], t0);
    // fusion conv, as an accumulating cin-slice of the 128-cin conv
    if (br == 0)
      conv3x3_k<64, false, false><<<dim3(256, 4), blk, 0, stream>>>(t0, fusw,          128 * 9, fusb, outp, 64);
    else
      conv3x3_k<64, false, true ><<<dim3(256, 4), blk, 0, stream>>>(t0, fusw + 64 * 9, 128 * 9, fusb, outp, 64);
  }
}

// Round 2
// 3355.116 us; speedup vs baseline: 1.3649x; 1.3649x over previous
//
#include <hip/hip_runtime.h>
#include <cstddef>

constexpr int IMG = 256;
constexpr int NPIX = 65536;

// ---------------------------------------------------------------------------
// Direct 3x3 conv, padding 1, NCHW. Tile = 32x16 pixels, 2 px/thread,
// 16 couts/block. Weights: compile-time offsets -> batched s_load_dwordx8.
// SUMIN: staged input = in + in2 + cbias[c]  (folds the mdcn partial-reduce
// and mdcn bias into the fusion conv's staging).
// ---------------------------------------------------------------------------
template<int CIN, int WROW, bool LRELU, bool ACCUM, bool SUMIN>
__global__ __launch_bounds__(256) void conv3x3_k(
    const float* __restrict__ in, const float* __restrict__ in2,
    const float* __restrict__ cbias,
    const float* __restrict__ w, const float* __restrict__ bias,
    float* __restrict__ out, int cout)
{
  constexpr int CC = 4;              // cin per LDS chunk
  __shared__ float sIn[CC][18 * 34];
  const int tid = threadIdx.x;
  const int ty0 = (blockIdx.x >> 3) << 4;   // 16 y-tiles
  const int tx0 = (blockIdx.x & 7) << 5;    // 8 x-tiles
  int co0 = blockIdx.y * 16;
  if (co0 + 16 > cout) co0 = cout - 16;     // tail: overlap-recompute, benign
  const int px = tid & 31, py0 = tid >> 5;  // rows py0 and py0+8

  float acc[16][2];
#pragma unroll
  for (int i = 0; i < 16; ++i) { acc[i][0] = 0.f; acc[i][1] = 0.f; }

  for (int c0 = 0; c0 < CIN; c0 += CC) {
    __syncthreads();
    for (int i = tid; i < CC * 612; i += 256) {
      int cs = i / 612, r = i - cs * 612;
      int ry = r / 34, rx = r - ry * 34;
      int gy = ty0 - 1 + ry, gx = tx0 - 1 + rx;
      float v = 0.f;
      if ((unsigned)gy < (unsigned)IMG && (unsigned)gx < (unsigned)IMG) {
        size_t gi = (size_t)(c0 + cs) * NPIX + gy * IMG + gx;
        v = in[gi];
        if (SUMIN) v += in2[gi] + cbias[c0 + cs];
      }
      sIn[cs][r] = v;
    }
    __syncthreads();
    const float* wp = w + (size_t)co0 * WROW + c0 * 9;
#pragma unroll
    for (int cs = 0; cs < CC; ++cs) {
      float v0[9], v1[9];
#pragma unroll
      for (int dy = 0; dy < 3; ++dy)
#pragma unroll
        for (int dx = 0; dx < 3; ++dx) {
          v0[dy * 3 + dx] = sIn[cs][(py0 + dy) * 34 + px + dx];
          v1[dy * 3 + dx] = sIn[cs][(py0 + 8 + dy) * 34 + px + dx];
        }
#pragma unroll
      for (int co = 0; co < 16; ++co) {
#pragma unroll
        for (int k = 0; k < 9; ++k) {
          float wk = wp[co * WROW + cs * 9 + k];   // compile-time imm offset
          acc[co][0] = fmaf(wk, v0[k], acc[co][0]);
          acc[co][1] = fmaf(wk, v1[k], acc[co][1]);
        }
      }
    }
  }
#pragma unroll
  for (int p = 0; p < 2; ++p) {
    const int oy = ty0 + py0 + 8 * p;
#pragma unroll
    for (int co = 0; co < 16; ++co) {
      size_t oidx = (size_t)(co0 + co) * NPIX + (size_t)oy * IMG + tx0 + px;
      if (ACCUM) {
        out[oidx] += acc[co][p];
      } else {
        float r = acc[co][p] + bias[co0 + co];
        if (LRELU) r = (r >= 0.f) ? r : 0.1f * r;
        out[oidx] = r;
      }
    }
  }
}

// ---------------------------------------------------------------------------
// feat CHW -> per-group layout featG[g][pix][8]  (32B records: line reuse
// across adjacent pixels, no cross-group overfetch)
// ---------------------------------------------------------------------------
__global__ __launch_bounds__(256) void featg_k(
    const float* __restrict__ in, float* __restrict__ out)
{
  int pix = blockIdx.x * 256 + threadIdx.x;
#pragma unroll
  for (int g = 0; g < 8; ++g) {
    float4 a, b;
    a.x = in[(size_t)(g * 8 + 0) * NPIX + pix];
    a.y = in[(size_t)(g * 8 + 1) * NPIX + pix];
    a.z = in[(size_t)(g * 8 + 2) * NPIX + pix];
    a.w = in[(size_t)(g * 8 + 3) * NPIX + pix];
    b.x = in[(size_t)(g * 8 + 4) * NPIX + pix];
    b.y = in[(size_t)(g * 8 + 5) * NPIX + pix];
    b.z = in[(size_t)(g * 8 + 6) * NPIX + pix];
    b.w = in[(size_t)(g * 8 + 7) * NPIX + pix];
    float* o = out + ((size_t)g * NPIX + pix) * 8;
    *reinterpret_cast<float4*>(o) = a;
    *reinterpret_cast<float4*>(o + 4) = b;
  }
}

// ---------------------------------------------------------------------------
// dcn weight transpose: wT[((g*9+k)*8 + c)*64 + o] = w[o*576 + g*72 + c*9 + k]
// -> per-tap weight block is 512 contiguous floats => s_load_dwordx8 batches.
// ---------------------------------------------------------------------------
__global__ __launch_bounds__(256) void wtprep_k(
    const float* __restrict__ w, float* __restrict__ wT)
{
  int i = blockIdx.x * 256 + threadIdx.x;   // 36864 total
  int o = i & 63;
  int r = i >> 6;
  int c = r & 7;
  int gk = r >> 3;
  int k = gk % 9;
  int g = gk / 9;
  wT[i] = w[(size_t)o * 576 + g * 72 + c * 9 + k];
}

// ---------------------------------------------------------------------------
// MDCN sample + partial GEMM. One thread = one pixel, 4 groups (by blockIdx.y).
// Writes 64-channel partial to part (p0 for groups 0-3, p1 for 4-7).
// Offset post-processing (tanh/sigmoid/flow) fused.
// ---------------------------------------------------------------------------
__global__ __launch_bounds__(256) void mdcn_sample_k(
    const float* __restrict__ featG, const float* __restrict__ o216,
    const float* __restrict__ flow, const float* __restrict__ wT,
    float* __restrict__ part0, float* __restrict__ part1)
{
  const int pix = blockIdx.x * 256 + threadIdx.x;
  const int h = pix >> 8, x = pix & 255;
  const float fy = flow[NPIX + pix];   // flow[:, ::-1]: even off-ch += flow[1]
  const float fx = flow[pix];

  float acc[64];
#pragma unroll
  for (int o = 0; o < 64; ++o) acc[o] = 0.f;

#pragma unroll 1
  for (int gg = 0; gg < 4; ++gg) {
    const int g = (blockIdx.y << 2) + gg;          // wave-uniform
    const float* fg = featG + (size_t)g * NPIX * 8;
#pragma unroll 1
    for (int k = 0; k < 9; ++k) {
      float oyr = o216[(size_t)(g * 18 + 2 * k) * NPIX + pix];
      float oxr = o216[(size_t)(g * 18 + 2 * k + 1) * NPIX + pix];
      float mkr = o216[(size_t)(144 + g * 9 + k) * NPIX + pix];
      float m = 1.f / (1.f + __expf(-mkr));
      float pyf = (float)h + (float)(k / 3 - 1) + 10.f * tanhf(oyr) + fy;
      float pxf = (float)x + (float)(k % 3 - 1) + 10.f * tanhf(oxr) + fx;
      float y0f = floorf(pyf), x0f = floorf(pxf);
      float ly = pyf - y0f, lx = pxf - x0f;
      int y0 = (int)y0f, x0 = (int)x0f;
      int y1 = y0 + 1, x1 = x0 + 1;
      bool vy0 = (unsigned)y0 < (unsigned)IMG, vy1 = (unsigned)y1 < (unsigned)IMG;
      bool vx0 = (unsigned)x0 < (unsigned)IMG, vx1 = (unsigned)x1 < (unsigned)IMG;
      int y0c = min(max(y0, 0), IMG - 1), y1c = min(max(y1, 0), IMG - 1);
      int x0c = min(max(x0, 0), IMG - 1), x1c = min(max(x1, 0), IMG - 1);
      float w00 = (vy0 && vx0) ? (1.f - ly) * (1.f - lx) * m : 0.f;
      float w01 = (vy0 && vx1) ? (1.f - ly) * lx * m : 0.f;
      float w10 = (vy1 && vx0) ? ly * (1.f - lx) * m : 0.f;
      float w11 = (vy1 && vx1) ? ly * lx * m : 0.f;
      const float* p00 = fg + (size_t)(y0c * IMG + x0c) * 8;
      const float* p01 = fg + (size_t)(y0c * IMG + x1c) * 8;
      const float* p10 = fg + (size_t)(y1c * IMG + x0c) * 8;
      const float* p11 = fg + (size_t)(y1c * IMG + x1c) * 8;
      float s[8];
#pragma unroll
      for (int q = 0; q < 2; ++q) {
        float4 a  = *reinterpret_cast<const float4*>(p00 + 4 * q);
        float4 b4 = *reinterpret_cast<const float4*>(p01 + 4 * q);
        float4 c4 = *reinterpret_cast<const float4*>(p10 + 4 * q);
        float4 d4 = *reinterpret_cast<const float4*>(p11 + 4 * q);
        s[4 * q + 0] = w00 * a.x + w01 * b4.x + w10 * c4.x + w11 * d4.x;
        s[4 * q + 1] = w00 * a.y + w01 * b4.y + w10 * c4.y + w11 * d4.y;
        s[4 * q + 2] = w00 * a.z + w01 * b4.z + w10 * c4.z + w11 * d4.z;
        s[4 * q + 3] = w00 * a.w + w01 * b4.w + w10 * c4.w + w11 * d4.w;
      }
      const float* wt = wT + (((size_t)g * 9 + k) << 9);  // 512 contiguous
#pragma unroll
      for (int c = 0; c < 8; ++c) {
#pragma unroll
        for (int o = 0; o < 64; ++o)
          acc[o] = fmaf(wt[c * 64 + o], s[c], acc[o]);
      }
    }
  }
  float* part = (blockIdx.y == 0) ? part0 : part1;
#pragma unroll
  for (int o = 0; o < 64; ++o)
    part[(size_t)o * NPIX + pix] = acc[o];
}

// ---------------------------------------------------------------------------
extern "C" void kernel_launch(void* const* d_in, const int* in_sizes, int n_in,
                              void* d_out, int out_size, void* d_ws, size_t ws_size,
                              hipStream_t stream)
{
  const float* feat[2]  = {(const float*)d_in[0], (const float*)d_in[1]};
  const float* extra[2] = {(const float*)d_in[2], (const float*)d_in[3]};
  const float* flow[2]  = {(const float*)d_in[4], (const float*)d_in[5]};
  const float* ow[2][4];
  const float* ob[2][4];
  for (int br = 0; br < 2; ++br)
    for (int j = 0; j < 4; ++j) {
      ow[br][j] = (const float*)d_in[6 + br * 8 + j * 2];
      ob[br][j] = (const float*)d_in[6 + br * 8 + j * 2 + 1];
    }
  const float* dcnw[2] = {(const float*)d_in[22], (const float*)d_in[24]};
  const float* dcnb[2] = {(const float*)d_in[23], (const float*)d_in[25]};
  const float* fusw = (const float*)d_in[26];
  const float* fusb = (const float*)d_in[27];

  float* ws = (float*)d_ws;
  float* t0 = ws;                        // 64 planes (conv buf / mdcn partial 0)
  float* t1 = ws + (size_t)64 * NPIX;    // 64 planes (conv buf / featG)
  float* t2 = ws + (size_t)128 * NPIX;   // 216 planes (o216)
  float* t3 = ws + (size_t)344 * NPIX;   // 64 planes (mdcn partial 1)
  float* wT = ws + (size_t)408 * NPIX;   // 36864 floats
  float* outp = (float*)d_out;

  dim3 blk(256);
  for (int br = 0; br < 2; ++br) {
    // offset network
    conv3x3_k<128, 1152, true,  false, false><<<dim3(128, 4),  blk, 0, stream>>>(
        extra[br], nullptr, nullptr, ow[br][0], ob[br][0], t0, 64);
    conv3x3_k<64, 576, true,  false, false><<<dim3(128, 4),  blk, 0, stream>>>(
        t0, nullptr, nullptr, ow[br][1], ob[br][1], t1, 64);
    conv3x3_k<64, 576, true,  false, false><<<dim3(128, 4),  blk, 0, stream>>>(
        t1, nullptr, nullptr, ow[br][2], ob[br][2], t0, 64);
    conv3x3_k<64, 576, false, false, false><<<dim3(128, 14), blk, 0, stream>>>(
        t0, nullptr, nullptr, ow[br][3], ob[br][3], t2, 216);
    // deformable conv (sample + partial GEMM, reduce folded into fusion conv)
    wtprep_k<<<dim3(144), blk, 0, stream>>>(dcnw[br], wT);
    featg_k<<<dim3(256), blk, 0, stream>>>(feat[br], t1);
    mdcn_sample_k<<<dim3(256, 2), blk, 0, stream>>>(t1, t2, flow[br], wT, t0, t3);
    // fusion conv on the cin-slice for this branch; staging sums partials+bias
    if (br == 0)
      conv3x3_k<64, 1152, false, false, true><<<dim3(128, 4), blk, 0, stream>>>(
          t0, t3, dcnb[0], fusw, fusb, outp, 64);
    else
      conv3x3_k<64, 1152, false, true,  true><<<dim3(128, 4), blk, 0, stream>>>(
          t0, t3, dcnb[1], fusw + 576, fusb, outp, 64);
  }
}